// Round 1
// baseline (1700.611 us; speedup 1.0000x reference)
//
#include <hip/hip_runtime.h>
#include <stdint.h>

typedef __attribute__((ext_vector_type(8))) __bf16 bf16x8;
typedef __attribute__((ext_vector_type(4))) float f32x4;

#define BM 128
#define BN 128
#define BK 32

__device__ __forceinline__ unsigned short f2bf_rne(float f) {
  unsigned int u = __builtin_bit_cast(unsigned int, f);
  u += 0x7FFFu + ((u >> 16) & 1u);
  return (unsigned short)(u >> 16);
}

// fp32 -> bf16 (RNE), 4 elems/thread/iter
__global__ void cvt_f32_to_bf16(const float* __restrict__ in,
                                unsigned short* __restrict__ out, long n4) {
  long stride = (long)gridDim.x * blockDim.x;
  for (long i = (long)blockIdx.x * blockDim.x + threadIdx.x; i < n4; i += stride) {
    float4 v = reinterpret_cast<const float4*>(in)[i];
    ushort4 o;
    o.x = f2bf_rne(v.x); o.y = f2bf_rne(v.y);
    o.z = f2bf_rne(v.z); o.w = f2bf_rne(v.w);
    reinterpret_cast<ushort4*>(out)[i] = o;
  }
}

// int32 (|v|<=127, exact in bf16) -> bf16
__global__ void cvt_i32_to_bf16(const int* __restrict__ in,
                                unsigned short* __restrict__ out, long n4) {
  long stride = (long)gridDim.x * blockDim.x;
  for (long i = (long)blockIdx.x * blockDim.x + threadIdx.x; i < n4; i += stride) {
    int4 v = reinterpret_cast<const int4*>(in)[i];
    ushort4 o;
    o.x = f2bf_rne((float)v.x); o.y = f2bf_rne((float)v.y);
    o.z = f2bf_rne((float)v.z); o.w = f2bf_rne((float)v.w);
    reinterpret_cast<ushort4*>(out)[i] = o;
  }
}

// global -> LDS direct, 16B/lane (dest must be uniform_base + lane*16)
#define GLDS16(g, l)                                                          \
  __builtin_amdgcn_global_load_lds(                                           \
      (const __attribute__((address_space(1))) unsigned int*)(g),             \
      (__attribute__((address_space(3))) unsigned int*)(l), 16, 0, 0)

// m97-structure GEMM: C[M][N] = A[M][K] * W[N][K]^T, epilogue *scale[n] + bias[n]
__global__ __launch_bounds__(256) void gemm_bf16_w8(
    const unsigned short* __restrict__ A,   // [M][K] bf16
    const unsigned short* __restrict__ W,   // [N][K] bf16 (unscaled int8 values)
    const float* __restrict__ scale,        // [N]
    const float* __restrict__ bias,         // [N]
    float* __restrict__ C,                  // [M][N] fp32
    int M, int N, int K) {
  __shared__ unsigned short As[BM * BK];   // 8 KiB, row-major [128][32]
  __shared__ unsigned short Ws[BN * BK];   // 8 KiB

  const int tid = threadIdx.x;
  const int nwg = gridDim.x;
  const int bid = blockIdx.x;
  // XCD-aware swizzle (bijective since nwg % 8 == 0; guarded anyway)
  const int wg = ((nwg & 7) == 0) ? ((bid & 7) * (nwg >> 3) + (bid >> 3)) : bid;
  const int mTiles = M / BM;
  const int bm = wg % mTiles;   // M-fast: consecutive wg share the W panel
  const int bn = wg / mTiles;

  const long aRow0 = (long)bm * BM;
  const long wRow0 = (long)bn * BN;

  // staging: thread t loads 16B; LDS linear offset = t*16 (+4096 for 2nd half)
  const int sr = tid >> 2;            // row 0..63 within half-tile
  const int sc = (tid & 3) << 3;      // k-elem 0,8,16,24
  const unsigned short* aSrc0 = A + (aRow0 + sr) * K + sc;
  const unsigned short* aSrc1 = aSrc0 + (long)64 * K;
  const unsigned short* wSrc0 = W + (wRow0 + sr) * K + sc;
  const unsigned short* wSrc1 = wSrc0 + (long)64 * K;
  unsigned short* aDst0 = &As[tid * 8];
  unsigned short* aDst1 = &As[2048 + tid * 8];
  unsigned short* wDst0 = &Ws[tid * 8];
  unsigned short* wDst1 = &Ws[2048 + tid * 8];

  // wave -> 64x64 output sub-tile
  const int lane = tid & 63;
  const int wid = tid >> 6;
  const int wr = (wid >> 1) << 6;     // 0 / 64
  const int wc = (wid & 1) << 6;
  const int lrow = lane & 15;
  const int lk = (lane >> 4) << 3;    // 0,8,16,24 (8 contiguous k per lane)

  const unsigned short* aRd = &As[(wr + lrow) * BK + lk];
  const unsigned short* wRd = &Ws[(wc + lrow) * BK + lk];

  f32x4 acc[4][4] = {};

  const int nk = K / BK;
  for (int kt = 0; kt < nk; ++kt) {
    GLDS16(aSrc0, aDst0);
    GLDS16(aSrc1, aDst1);
    GLDS16(wSrc0, wDst0);
    GLDS16(wSrc1, wDst1);
    aSrc0 += BK; aSrc1 += BK; wSrc0 += BK; wSrc1 += BK;
    __syncthreads();  // vmcnt(0) drain: staged data visible to all waves

    bf16x8 af[4], wf[4];
#pragma unroll
    for (int m = 0; m < 4; ++m)
      af[m] = *reinterpret_cast<const bf16x8*>(aRd + m * 16 * BK);
#pragma unroll
    for (int n = 0; n < 4; ++n)
      wf[n] = *reinterpret_cast<const bf16x8*>(wRd + n * 16 * BK);
#pragma unroll
    for (int m = 0; m < 4; ++m)
#pragma unroll
      for (int n = 0; n < 4; ++n)
        acc[m][n] = __builtin_amdgcn_mfma_f32_16x16x32_bf16(af[m], wf[n],
                                                            acc[m][n], 0, 0, 0);
    __syncthreads();  // all waves done reading before next stage overwrites
  }

  // epilogue: C/D layout col = lane&15, row = (lane>>4)*4 + reg  [m89/m91]
  const long cCol0 = wRow0 + wc + lrow;
  float scl[4], bs[4];
#pragma unroll
  for (int n = 0; n < 4; ++n) {
    scl[n] = scale[cCol0 + n * 16];
    bs[n] = bias[cCol0 + n * 16];
  }
  const long cRow0 = aRow0 + wr + ((lane >> 4) << 2);
#pragma unroll
  for (int m = 0; m < 4; ++m) {
#pragma unroll
    for (int v = 0; v < 4; ++v) {
      float* cp = C + (cRow0 + m * 16 + v) * N + cCol0;
#pragma unroll
      for (int n = 0; n < 4; ++n)
        cp[n * 16] = acc[m][n][v] * scl[n] + bs[n];
    }
  }
}

// correctness-only fallback if ws_size < A_bf16 + W_bf16 (should not trigger)
__global__ void naive_w8a16(const float* __restrict__ inp,
                            const int* __restrict__ qw,
                            const float* __restrict__ scale,
                            const float* __restrict__ bias,
                            float* __restrict__ out, long M, long N, long K) {
  long idx = (long)blockIdx.x * blockDim.x + threadIdx.x;
  if (idx >= M * N) return;
  long col = idx % N, row = idx / N;
  const float* a = inp + row * K;
  const int* w = qw + col * K;
  float s = 0.f;
  for (long k = 0; k < K; k += 4) {
    float4 av = *reinterpret_cast<const float4*>(&a[k]);
    int4 wv = *reinterpret_cast<const int4*>(&w[k]);
    s += av.x * (float)wv.x + av.y * (float)wv.y + av.z * (float)wv.z +
         av.w * (float)wv.w;
  }
  out[idx] = s * scale[col] + bias[col];
}

extern "C" void kernel_launch(void* const* d_in, const int* in_sizes, int n_in,
                              void* d_out, int out_size, void* d_ws,
                              size_t ws_size, hipStream_t stream) {
  const float* inp = (const float*)d_in[0];   // [B,S,D_IN] fp32
  const int* qw = (const int*)d_in[1];        // [D_OUT,D_IN] int32
  const float* scale = (const float*)d_in[2]; // [D_OUT]
  const float* bias = (const float*)d_in[3];  // [D_OUT]
  float* out = (float*)d_out;                 // [B,S,D_OUT] fp32

  const long N = in_sizes[2];                 // 16384
  const long K = (long)in_sizes[1] / N;       // 4096
  const long M = (long)in_sizes[0] / K;       // 8192

  const size_t aBytes = (size_t)M * K * 2;    // 64 MiB
  const size_t wBytes = (size_t)N * K * 2;    // 128 MiB

  if (ws_size >= aBytes + wBytes && (M % BM) == 0 && (N % BN) == 0 &&
      (K % BK) == 0) {
    unsigned short* Abf = (unsigned short*)d_ws;
    unsigned short* Wbf = (unsigned short*)((char*)d_ws + aBytes);
    cvt_f32_to_bf16<<<2048, 256, 0, stream>>>(inp, Abf, M * K / 4);
    cvt_i32_to_bf16<<<2048, 256, 0, stream>>>(qw, Wbf, N * K / 4);
    const int nwg = (int)((M / BM) * (N / BN));  // 8192
    gemm_bf16_w8<<<nwg, 256, 0, stream>>>(Abf, Wbf, scale, bias, out, (int)M,
                                          (int)N, (int)K);
  } else {
    long total = M * N;
    naive_w8a16<<<(int)((total + 255) / 256), 256, 0, stream>>>(
        inp, qw, scale, bias, out, M, N, K);
  }
}

// Round 2
// 1692.346 us; speedup vs baseline: 1.0049x; 1.0049x over previous
//
#include <hip/hip_runtime.h>
#include <stdint.h>

typedef __attribute__((ext_vector_type(8))) __bf16 bf16x8;
typedef __attribute__((ext_vector_type(4))) float f32x4;

#define BM 256
#define BN 256
#define BKT 64   // K elems per tile; split into 2 K-halves of 32

__device__ __forceinline__ unsigned short f2bf_rne(float f) {
  unsigned int u = __builtin_bit_cast(unsigned int, f);
  u += 0x7FFFu + ((u >> 16) & 1u);
  return (unsigned short)(u >> 16);
}

__global__ void cvt_f32_to_bf16(const float* __restrict__ in,
                                unsigned short* __restrict__ out, long n4) {
  long stride = (long)gridDim.x * blockDim.x;
  for (long i = (long)blockIdx.x * blockDim.x + threadIdx.x; i < n4; i += stride) {
    float4 v = reinterpret_cast<const float4*>(in)[i];
    ushort4 o;
    o.x = f2bf_rne(v.x); o.y = f2bf_rne(v.y);
    o.z = f2bf_rne(v.z); o.w = f2bf_rne(v.w);
    reinterpret_cast<ushort4*>(out)[i] = o;
  }
}

__global__ void cvt_i32_to_bf16(const int* __restrict__ in,
                                unsigned short* __restrict__ out, long n4) {
  long stride = (long)gridDim.x * blockDim.x;
  for (long i = (long)blockIdx.x * blockDim.x + threadIdx.x; i < n4; i += stride) {
    int4 v = reinterpret_cast<const int4*>(in)[i];
    ushort4 o;
    o.x = f2bf_rne((float)v.x); o.y = f2bf_rne((float)v.y);
    o.z = f2bf_rne((float)v.z); o.w = f2bf_rne((float)v.w);
    reinterpret_cast<ushort4*>(out)[i] = o;
  }
}

#define GLDS16(g, l)                                                          \
  __builtin_amdgcn_global_load_lds(                                           \
      (const __attribute__((address_space(1))) unsigned int*)(g),             \
      (__attribute__((address_space(3))) unsigned int*)(l), 16, 0, 0)

// 256x256 8-phase GEMM (m201-template port). C = A[M][K] * W[N][K]^T,
// epilogue *scale[n] + bias[n]. K-half LDS layout [256][32] bf16 (64B rows):
// frag reads are bank-balanced without swizzle; gload_lds dest stays linear.
__global__ __launch_bounds__(512, 2) void gemm256_8ph(
    const unsigned short* __restrict__ A,   // [M][K] bf16
    const unsigned short* __restrict__ W,   // [N][K] bf16
    const float* __restrict__ scale,        // [N]
    const float* __restrict__ bias,         // [N]
    float* __restrict__ C,                  // [M][N] f32
    int M, int N, int K) {
  // [buf][kh][256*32] shorts: 16 KiB per half-region; 64 KiB per tensor; 128 KiB total
  __shared__ __align__(16) unsigned short As[2][2][256 * 32];
  __shared__ __align__(16) unsigned short Bs[2][2][256 * 32];

  const int tid = threadIdx.x;
  const int lane = tid & 63;
  const int wv = tid >> 6;       // 0..7
  const int wm = wv >> 2;        // 0..1  (wave row: 128 rows each)
  const int wn = wv & 3;         // 0..3  (wave col: 64 cols each)

  const int nwg = gridDim.x;
  const int bid = blockIdx.x;
  const int wg = ((nwg & 7) == 0) ? ((bid & 7) * (nwg >> 3) + (bid >> 3)) : bid;
  const int mT = M / BM;
  const int bm = wg % mT;        // M-fast: neighbors share W panel
  const int bn = wg / mT;

  const long aRow0 = (long)bm * BM;
  const long wRow0 = (long)bn * BN;

  // ---- staging geometry: one 16 KiB half staged by 16 wave-chunks of 1 KiB.
  // wave wv stages chunks c0=wv (issue0) and c1=8+wv (issue1).
  // chunk c covers rows 16c..16c+15; lane: row=16c+(lane>>2), 16B at col (lane&3)*8.
  const int c0 = wv, c1 = 8 + wv;
  const int sr0 = 16 * c0 + (lane >> 2);
  const int sr1 = 16 * c1 + (lane >> 2);
  const int sc = (lane & 3) * 8;
  const unsigned short* aS0 = A + (aRow0 + sr0) * (long)K + sc;
  const unsigned short* aS1 = A + (aRow0 + sr1) * (long)K + sc;
  const unsigned short* wS0 = W + (wRow0 + sr0) * (long)K + sc;
  const unsigned short* wS1 = W + (wRow0 + sr1) * (long)K + sc;
  const int d0 = c0 * 512 + lane * 8;   // ushort offset into a half-region
  const int d1 = c1 * 512 + lane * 8;

  // ---- ds_read bases (ushort idx in half-region): row*32 + (lane>>4)*8
  const int rdA = (wm * 128 + (lane & 15)) * 32 + (lane >> 4) * 8;
  const int rdB = (wn * 64 + (lane & 15)) * 32 + (lane >> 4) * 8;

  f32x4 acc[8][4] = {};

  const int nk = K / BKT;

  // ---- prologue: stage tile 0 (order: A-kh0, B-kh0, A-kh1, B-kh1)
  GLDS16(aS0, &As[0][0][d0]);
  GLDS16(aS1, &As[0][0][d1]);
  GLDS16(wS0, &Bs[0][0][d0]);
  GLDS16(wS1, &Bs[0][0][d1]);
  GLDS16(aS0 + 32, &As[0][1][d0]);
  GLDS16(aS1 + 32, &As[0][1][d1]);
  GLDS16(wS0 + 32, &Bs[0][1][d0]);
  GLDS16(wS1 + 32, &Bs[0][1][d1]);
  asm volatile("s_waitcnt vmcnt(4)" ::: "memory");  // tile0 kh0 resident
  __builtin_amdgcn_s_barrier();

  for (int kt = 0; kt < nk; ++kt) {
    const int cur = kt & 1, nxt = cur ^ 1;
    const long koff = (long)(((kt + 1) < nk) ? (kt + 1) : 0) * BKT;  // wrap: harmless prefetch
#pragma unroll
    for (int ks = 0; ks < 2; ++ks) {
#pragma unroll
      for (int mh = 0; mh < 2; ++mh) {
        // 8 x ds_read_b128 for this phase's fragments
        bf16x8 af[4], bfr[4];
#pragma unroll
        for (int i = 0; i < 4; ++i)
          af[i] = *reinterpret_cast<const bf16x8*>(
              &As[cur][ks][rdA + (mh * 64 + i * 16) * 32]);
#pragma unroll
        for (int j = 0; j < 4; ++j)
          bfr[j] = *reinterpret_cast<const bf16x8*>(
              &Bs[cur][ks][rdB + (j * 16) * 32]);
        // stage one half of tile kt+1: p0:A-kh0 p1:B-kh0 p2:A-kh1 p3:B-kh1
        const int p = ks * 2 + mh;
        if (p == 0) {
          GLDS16(aS0 + koff, &As[nxt][0][d0]);
          GLDS16(aS1 + koff, &As[nxt][0][d1]);
        } else if (p == 1) {
          GLDS16(wS0 + koff, &Bs[nxt][0][d0]);
          GLDS16(wS1 + koff, &Bs[nxt][0][d1]);
        } else if (p == 2) {
          GLDS16(aS0 + koff + 32, &As[nxt][1][d0]);
          GLDS16(aS1 + koff + 32, &As[nxt][1][d1]);
        } else {
          GLDS16(wS0 + koff + 32, &Bs[nxt][1][d0]);
          GLDS16(wS1 + koff + 32, &Bs[nxt][1][d1]);
        }
        asm volatile("" ::: "memory");  // pin reads+stages before barrier
        __builtin_amdgcn_s_barrier();
        __builtin_amdgcn_s_setprio(1);
#pragma unroll
        for (int i = 0; i < 4; ++i)
#pragma unroll
          for (int j = 0; j < 4; ++j)
            acc[mh * 4 + i][j] = __builtin_amdgcn_mfma_f32_16x16x32_bf16(
                af[i], bfr[j], acc[mh * 4 + i][j], 0, 0, 0);
        __builtin_amdgcn_s_setprio(0);
        // counted waits, once per 2 phases (never drain to 0):
        // p==1: cur.kh1 (issued 2 phases ago) must be resident for p2/p3 reads
        // p==3: nxt.kh0 must be resident for next tile's p0/p1 reads
        if (p == 1 || p == 3)
          asm volatile("s_waitcnt vmcnt(4)" ::: "memory");
        __builtin_amdgcn_s_barrier();
      }
    }
  }

  // ---- epilogue: C/D frag layout col=lane&15, row=(lane>>4)*4+v
  const long col0 = wRow0 + wn * 64 + (lane & 15);
  float scl[4], bs[4];
#pragma unroll
  for (int j = 0; j < 4; ++j) {
    scl[j] = scale[col0 + j * 16];
    bs[j] = bias[col0 + j * 16];
  }
  const long row0 = aRow0 + wm * 128 + ((lane >> 4) << 2);
#pragma unroll
  for (int i = 0; i < 8; ++i) {
#pragma unroll
    for (int v = 0; v < 4; ++v) {
      float* cp = C + (row0 + i * 16 + v) * (long)N + col0;
#pragma unroll
      for (int j = 0; j < 4; ++j)
        cp[j * 16] = acc[i][j][v] * scl[j] + bs[j];
    }
  }
}

// correctness-only fallback
__global__ void naive_w8a16(const float* __restrict__ inp,
                            const int* __restrict__ qw,
                            const float* __restrict__ scale,
                            const float* __restrict__ bias,
                            float* __restrict__ out, long M, long N, long K) {
  long idx = (long)blockIdx.x * blockDim.x + threadIdx.x;
  if (idx >= M * N) return;
  long col = idx % N, row = idx / N;
  const float* a = inp + row * K;
  const int* w = qw + col * K;
  float s = 0.f;
  for (long k = 0; k < K; k += 4) {
    float4 av = *reinterpret_cast<const float4*>(&a[k]);
    int4 wv = *reinterpret_cast<const int4*>(&w[k]);
    s += av.x * (float)wv.x + av.y * (float)wv.y + av.z * (float)wv.z +
         av.w * (float)wv.w;
  }
  out[idx] = s * scale[col] + bias[col];
}

extern "C" void kernel_launch(void* const* d_in, const int* in_sizes, int n_in,
                              void* d_out, int out_size, void* d_ws,
                              size_t ws_size, hipStream_t stream) {
  const float* inp = (const float*)d_in[0];   // [B,S,D_IN] f32
  const int* qw = (const int*)d_in[1];        // [D_OUT,D_IN] i32
  const float* scale = (const float*)d_in[2]; // [D_OUT]
  const float* bias = (const float*)d_in[3];  // [D_OUT]
  float* out = (float*)d_out;                 // [B,S,D_OUT] f32

  const long N = in_sizes[2];                 // 16384
  const long K = (long)in_sizes[1] / N;       // 4096
  const long M = (long)in_sizes[0] / K;       // 8192

  const size_t aBytes = (size_t)M * K * 2;
  const size_t wBytes = (size_t)N * K * 2;

  if (ws_size >= aBytes + wBytes && (M % BM) == 0 && (N % BN) == 0 &&
      (K % BKT) == 0 && (K / BKT) >= 2) {
    unsigned short* Abf = (unsigned short*)d_ws;
    unsigned short* Wbf = (unsigned short*)((char*)d_ws + aBytes);
    cvt_f32_to_bf16<<<2048, 256, 0, stream>>>(inp, Abf, M * K / 4);
    cvt_i32_to_bf16<<<2048, 256, 0, stream>>>(qw, Wbf, N * K / 4);
    const int nwg = (int)((M / BM) * (N / BN));  // 2048
    gemm256_8ph<<<nwg, 512, 0, stream>>>(Abf, Wbf, scale, bias, out, (int)M,
                                         (int)N, (int)K);
  } else {
    long total = M * N;
    naive_w8a16<<<(int)((total + 255) / 256), 256, 0, stream>>>(
        inp, qw, scale, bias, out, M, N, K);
  }
}

// Round 3
// 1624.931 us; speedup vs baseline: 1.0466x; 1.0415x over previous
//
#include <hip/hip_runtime.h>
#include <stdint.h>

typedef __attribute__((ext_vector_type(8))) __bf16 bf16x8;
typedef __attribute__((ext_vector_type(4))) float f32x4;

#define BM 256
#define BN 256
#define BKT 64   // K elems per tile; split into 2 K-halves of 32

__device__ __forceinline__ unsigned short f2bf_rne(float f) {
  unsigned int u = __builtin_bit_cast(unsigned int, f);
  u += 0x7FFFu + ((u >> 16) & 1u);
  return (unsigned short)(u >> 16);
}

__global__ void cvt_f32_to_bf16(const float* __restrict__ in,
                                unsigned short* __restrict__ out, long n4) {
  long stride = (long)gridDim.x * blockDim.x;
  for (long i = (long)blockIdx.x * blockDim.x + threadIdx.x; i < n4; i += stride) {
    float4 v = reinterpret_cast<const float4*>(in)[i];
    ushort4 o;
    o.x = f2bf_rne(v.x); o.y = f2bf_rne(v.y);
    o.z = f2bf_rne(v.z); o.w = f2bf_rne(v.w);
    reinterpret_cast<ushort4*>(out)[i] = o;
  }
}

__global__ void cvt_i32_to_bf16(const int* __restrict__ in,
                                unsigned short* __restrict__ out, long n4) {
  long stride = (long)gridDim.x * blockDim.x;
  for (long i = (long)blockIdx.x * blockDim.x + threadIdx.x; i < n4; i += stride) {
    int4 v = reinterpret_cast<const int4*>(in)[i];
    ushort4 o;
    o.x = f2bf_rne((float)v.x); o.y = f2bf_rne((float)v.y);
    o.z = f2bf_rne((float)v.z); o.w = f2bf_rne((float)v.w);
    reinterpret_cast<ushort4*>(out)[i] = o;
  }
}

#define GLDS16(g, l)                                                          \
  __builtin_amdgcn_global_load_lds(                                           \
      (const __attribute__((address_space(1))) unsigned int*)(g),             \
      (__attribute__((address_space(3))) unsigned int*)(l), 16, 0, 0)

// 256x256 8-phase GEMM with T2 bank-conflict swizzle.
// LDS K-half layout [256][32] bf16; within each 1024B chunk (16 rows x 4
// 16B-slots), physical slot (r,s) holds logical (r, s ^ ((r>>1)&3)).
// Write side: gload_lds dest stays LINEAR; the global SOURCE column is
// inverse-permuted. Read side: ds_read slot index XORed the same way.
__global__ __launch_bounds__(512, 2) void gemm256_8ph(
    const unsigned short* __restrict__ A,   // [M][K] bf16
    const unsigned short* __restrict__ W,   // [N][K] bf16
    const float* __restrict__ scale,        // [N]
    const float* __restrict__ bias,         // [N]
    float* __restrict__ C,                  // [M][N] f32
    int M, int N, int K) {
  __shared__ __align__(16) unsigned short As[2][2][256 * 32];
  __shared__ __align__(16) unsigned short Bs[2][2][256 * 32];

  const int tid = threadIdx.x;
  const int lane = tid & 63;
  const int wv = tid >> 6;       // 0..7
  const int wm = wv >> 2;        // 0..1  (wave row: 128 rows)
  const int wn = wv & 3;         // 0..3  (wave col: 64 cols)

  const int nwg = gridDim.x;
  const int bid = blockIdx.x;
  const int wg = ((nwg & 7) == 0) ? ((bid & 7) * (nwg >> 3) + (bid >> 3)) : bid;
  const int mT = M / BM;
  const int bm = wg % mT;        // M-fast: neighbors share W panel
  const int bn = wg / mT;

  const long aRow0 = (long)bm * BM;
  const long wRow0 = (long)bn * BN;

  // ---- staging: chunk c = 16 rows x 64B. lane l writes LINEAR dest slot
  // p=l (row r=l>>2, slot s=l&3); it must carry logical slot s^f(r),
  // f(r)=(r>>1)&3 = (l>>3)&3. So source k-offset is swizzled:
  const int c0 = wv, c1 = 8 + wv;
  const int sr0 = 16 * c0 + (lane >> 2);
  const int sr1 = 16 * c1 + (lane >> 2);
  const int sc = (((lane & 3) ^ ((lane >> 3) & 3))) * 8;  // inverse-swz source
  const unsigned short* aS0 = A + (aRow0 + sr0) * (long)K + sc;
  const unsigned short* aS1 = A + (aRow0 + sr1) * (long)K + sc;
  const unsigned short* wS0 = W + (wRow0 + sr0) * (long)K + sc;
  const unsigned short* wS1 = W + (wRow0 + sr1) * (long)K + sc;
  const int d0 = c0 * 512 + lane * 8;   // linear ushort offset in half-region
  const int d1 = c1 * 512 + lane * 8;

  // ---- ds_read bases: row*32 + swizzled-slot*8. Row bits 1..2 within every
  // 16-row block equal (lane>>1)&3, so the XOR term is lane-constant:
  const int sx = (lane >> 4) ^ ((lane >> 1) & 3);
  const int rdA = (wm * 128 + (lane & 15)) * 32 + sx * 8;
  const int rdB = (wn * 64 + (lane & 15)) * 32 + sx * 8;

  f32x4 acc[8][4] = {};

  const int nk = K / BKT;

  // ---- prologue: stage tile 0 (A-kh0, B-kh0, A-kh1, B-kh1)
  GLDS16(aS0, &As[0][0][d0]);
  GLDS16(aS1, &As[0][0][d1]);
  GLDS16(wS0, &Bs[0][0][d0]);
  GLDS16(wS1, &Bs[0][0][d1]);
  GLDS16(aS0 + 32, &As[0][1][d0]);
  GLDS16(aS1 + 32, &As[0][1][d1]);
  GLDS16(wS0 + 32, &Bs[0][1][d0]);
  GLDS16(wS1 + 32, &Bs[0][1][d1]);
  asm volatile("s_waitcnt vmcnt(4)" ::: "memory");  // tile0 kh0 resident
  __builtin_amdgcn_s_barrier();

  for (int kt = 0; kt < nk; ++kt) {
    const int cur = kt & 1, nxt = cur ^ 1;
    const long koff = (long)(((kt + 1) < nk) ? (kt + 1) : 0) * BKT;
#pragma unroll
    for (int ks = 0; ks < 2; ++ks) {
#pragma unroll
      for (int mh = 0; mh < 2; ++mh) {
        bf16x8 af[4], bfr[4];
#pragma unroll
        for (int i = 0; i < 4; ++i)
          af[i] = *reinterpret_cast<const bf16x8*>(
              &As[cur][ks][rdA + (mh * 64 + i * 16) * 32]);
#pragma unroll
        for (int j = 0; j < 4; ++j)
          bfr[j] = *reinterpret_cast<const bf16x8*>(
              &Bs[cur][ks][rdB + (j * 16) * 32]);
        const int p = ks * 2 + mh;
        if (p == 0) {
          GLDS16(aS0 + koff, &As[nxt][0][d0]);
          GLDS16(aS1 + koff, &As[nxt][0][d1]);
        } else if (p == 1) {
          GLDS16(wS0 + koff, &Bs[nxt][0][d0]);
          GLDS16(wS1 + koff, &Bs[nxt][0][d1]);
        } else if (p == 2) {
          GLDS16(aS0 + koff + 32, &As[nxt][1][d0]);
          GLDS16(aS1 + koff + 32, &As[nxt][1][d1]);
        } else {
          GLDS16(wS0 + koff + 32, &Bs[nxt][1][d0]);
          GLDS16(wS1 + koff + 32, &Bs[nxt][1][d1]);
        }
        asm volatile("" ::: "memory");
        __builtin_amdgcn_s_barrier();
        __builtin_amdgcn_s_setprio(1);
#pragma unroll
        for (int i = 0; i < 4; ++i)
#pragma unroll
          for (int j = 0; j < 4; ++j)
            acc[mh * 4 + i][j] = __builtin_amdgcn_mfma_f32_16x16x32_bf16(
                af[i], bfr[j], acc[mh * 4 + i][j], 0, 0, 0);
        __builtin_amdgcn_s_setprio(0);
        // counted waits (never 0 in-loop):
        // p==1: cur.kh1 must be resident before p2/p3 read it
        // p==3: nxt.kh0 must be resident before next tile's p0/p1
        if (p == 1 || p == 3)
          asm volatile("s_waitcnt vmcnt(4)" ::: "memory");
        __builtin_amdgcn_s_barrier();
      }
    }
  }

  // ---- epilogue: C/D frag layout col=lane&15, row=(lane>>4)*4+v
  const long col0 = wRow0 + wn * 64 + (lane & 15);
  float scl[4], bs[4];
#pragma unroll
  for (int j = 0; j < 4; ++j) {
    scl[j] = scale[col0 + j * 16];
    bs[j] = bias[col0 + j * 16];
  }
  const long row0 = aRow0 + wm * 128 + ((lane >> 4) << 2);
#pragma unroll
  for (int i = 0; i < 8; ++i) {
#pragma unroll
    for (int v = 0; v < 4; ++v) {
      float* cp = C + (row0 + i * 16 + v) * (long)N + col0;
#pragma unroll
      for (int j = 0; j < 4; ++j)
        cp[j * 16] = acc[i][j][v] * scl[j] + bs[j];
    }
  }
}

// correctness-only fallback
__global__ void naive_w8a16(const float* __restrict__ inp,
                            const int* __restrict__ qw,
                            const float* __restrict__ scale,
                            const float* __restrict__ bias,
                            float* __restrict__ out, long M, long N, long K) {
  long idx = (long)blockIdx.x * blockDim.x + threadIdx.x;
  if (idx >= M * N) return;
  long col = idx % N, row = idx / N;
  const float* a = inp + row * K;
  const int* w = qw + col * K;
  float s = 0.f;
  for (long k = 0; k < K; k += 4) {
    float4 av = *reinterpret_cast<const float4*>(&a[k]);
    int4 wv = *reinterpret_cast<const int4*>(&w[k]);
    s += av.x * (float)wv.x + av.y * (float)wv.y + av.z * (float)wv.z +
         av.w * (float)wv.w;
  }
  out[idx] = s * scale[col] + bias[col];
}

extern "C" void kernel_launch(void* const* d_in, const int* in_sizes, int n_in,
                              void* d_out, int out_size, void* d_ws,
                              size_t ws_size, hipStream_t stream) {
  const float* inp = (const float*)d_in[0];   // [B,S,D_IN] f32
  const int* qw = (const int*)d_in[1];        // [D_OUT,D_IN] i32
  const float* scale = (const float*)d_in[2]; // [D_OUT]
  const float* bias = (const float*)d_in[3];  // [D_OUT]
  float* out = (float*)d_out;                 // [B,S,D_OUT] f32

  const long N = in_sizes[2];                 // 16384
  const long K = (long)in_sizes[1] / N;       // 4096
  const long M = (long)in_sizes[0] / K;       // 8192

  const size_t aBytes = (size_t)M * K * 2;
  const size_t wBytes = (size_t)N * K * 2;

  if (ws_size >= aBytes + wBytes && (M % BM) == 0 && (N % BN) == 0 &&
      (K % BKT) == 0 && (K / BKT) >= 2) {
    unsigned short* Abf = (unsigned short*)d_ws;
    unsigned short* Wbf = (unsigned short*)((char*)d_ws + aBytes);
    cvt_f32_to_bf16<<<2048, 256, 0, stream>>>(inp, Abf, M * K / 4);
    cvt_i32_to_bf16<<<2048, 256, 0, stream>>>(qw, Wbf, N * K / 4);
    const int nwg = (int)((M / BM) * (N / BN));  // 2048
    gemm256_8ph<<<nwg, 512, 0, stream>>>(Abf, Wbf, scale, bias, out, (int)M,
                                         (int)N, (int)K);
  } else {
    long total = M * N;
    naive_w8a16<<<(int)((total + 255) / 256), 256, 0, stream>>>(
        inp, qw, scale, bias, out, M, N, K);
  }
}

// Round 4
// 1605.958 us; speedup vs baseline: 1.0589x; 1.0118x over previous
//
#include <hip/hip_runtime.h>
#include <stdint.h>

typedef __attribute__((ext_vector_type(8))) __bf16 bf16x8;
typedef __attribute__((ext_vector_type(4))) float f32x4;

#define BM 256
#define BN 256
#define BKT 64   // K elems per tile; split into 2 K-halves of 32

__device__ __forceinline__ unsigned short f2bf_rne(float f) {
  unsigned int u = __builtin_bit_cast(unsigned int, f);
  u += 0x7FFFu + ((u >> 16) & 1u);
  return (unsigned short)(u >> 16);
}

__global__ void cvt_f32_to_bf16(const float* __restrict__ in,
                                unsigned short* __restrict__ out, long n4) {
  long stride = (long)gridDim.x * blockDim.x;
  for (long i = (long)blockIdx.x * blockDim.x + threadIdx.x; i < n4; i += stride) {
    float4 v = reinterpret_cast<const float4*>(in)[i];
    ushort4 o;
    o.x = f2bf_rne(v.x); o.y = f2bf_rne(v.y);
    o.z = f2bf_rne(v.z); o.w = f2bf_rne(v.w);
    reinterpret_cast<ushort4*>(out)[i] = o;
  }
}

__global__ void cvt_i32_to_bf16(const int* __restrict__ in,
                                unsigned short* __restrict__ out, long n4) {
  long stride = (long)gridDim.x * blockDim.x;
  for (long i = (long)blockIdx.x * blockDim.x + threadIdx.x; i < n4; i += stride) {
    int4 v = reinterpret_cast<const int4*>(in)[i];
    ushort4 o;
    o.x = f2bf_rne((float)v.x); o.y = f2bf_rne((float)v.y);
    o.z = f2bf_rne((float)v.z); o.w = f2bf_rne((float)v.w);
    reinterpret_cast<ushort4*>(out)[i] = o;
  }
}

#define GLDS16(g, l)                                                          \
  __builtin_amdgcn_global_load_lds(                                           \
      (const __attribute__((address_space(1))) unsigned int*)(g),             \
      (__attribute__((address_space(3))) unsigned int*)(l), 16, 0, 0)

// 256x256 8-phase GEMM, T2-swizzled, 24-read/K-tile fragment schedule.
// LDS K-half layout [256][32] bf16; within each 1024B chunk (16 rows x 4
// 16B-slots), physical slot (r,s) holds logical (r, s ^ ((r>>1)&3)).
// Write: linear gload_lds dest + inverse-permuted global source column.
// Read: ds_read slot index XORed the same way.
// B fragments for each K-half are read ONCE and held in VGPRs across both
// mh phases (24 ds_read_b128 per wave per K-tile = the minimum).
__global__ __launch_bounds__(512, 2) void gemm256_8ph(
    const unsigned short* __restrict__ A,   // [M][K] bf16
    const unsigned short* __restrict__ W,   // [N][K] bf16
    const float* __restrict__ scale,        // [N]
    const float* __restrict__ bias,         // [N]
    float* __restrict__ C,                  // [M][N] f32
    int M, int N, int K) {
  __shared__ __align__(16) unsigned short As[2][2][256 * 32];
  __shared__ __align__(16) unsigned short Bs[2][2][256 * 32];

  const int tid = threadIdx.x;
  const int lane = tid & 63;
  const int wv = tid >> 6;       // 0..7
  const int wm = wv >> 2;        // 0..1  (wave row: 128 rows)
  const int wn = wv & 3;         // 0..3  (wave col: 64 cols)

  const int nwg = gridDim.x;
  const int bid = blockIdx.x;
  const int wg = ((nwg & 7) == 0) ? ((bid & 7) * (nwg >> 3) + (bid >> 3)) : bid;
  const int mT = M / BM;
  const int bm = wg % mT;        // M-fast: neighbors share W panel
  const int bn = wg / mT;

  const long aRow0 = (long)bm * BM;
  const long wRow0 = (long)bn * BN;

  // ---- staging: chunk c = 16 rows x 64B. lane l writes LINEAR dest slot
  // p=l (row r=l>>2, slot s=l&3); it must carry logical slot s^f(r),
  // f(r)=(r>>1)&3 = (l>>3)&3. So source k-offset is swizzled:
  const int c0 = wv, c1 = 8 + wv;
  const int sr0 = 16 * c0 + (lane >> 2);
  const int sr1 = 16 * c1 + (lane >> 2);
  const int sc = (((lane & 3) ^ ((lane >> 3) & 3))) * 8;  // inverse-swz source
  const unsigned short* aS0 = A + (aRow0 + sr0) * (long)K + sc;
  const unsigned short* aS1 = A + (aRow0 + sr1) * (long)K + sc;
  const unsigned short* wS0 = W + (wRow0 + sr0) * (long)K + sc;
  const unsigned short* wS1 = W + (wRow0 + sr1) * (long)K + sc;
  const int d0 = c0 * 512 + lane * 8;   // linear ushort offset in half-region
  const int d1 = c1 * 512 + lane * 8;

  // ---- ds_read bases: row*32 + swizzled-slot*8. Row bits 1..2 within every
  // 16-row block equal (lane>>1)&3, so the XOR term is lane-constant:
  const int sx = (lane >> 4) ^ ((lane >> 1) & 3);
  const int rdA = (wm * 128 + (lane & 15)) * 32 + sx * 8;
  const int rdB = (wn * 64 + (lane & 15)) * 32 + sx * 8;

  f32x4 acc[8][4] = {};

  const int nk = K / BKT;

  // ---- prologue: stage tile 0 (A-kh0, B-kh0, A-kh1, B-kh1)
  GLDS16(aS0, &As[0][0][d0]);
  GLDS16(aS1, &As[0][0][d1]);
  GLDS16(wS0, &Bs[0][0][d0]);
  GLDS16(wS1, &Bs[0][0][d1]);
  GLDS16(aS0 + 32, &As[0][1][d0]);
  GLDS16(aS1 + 32, &As[0][1][d1]);
  GLDS16(wS0 + 32, &Bs[0][1][d0]);
  GLDS16(wS1 + 32, &Bs[0][1][d1]);
  asm volatile("s_waitcnt vmcnt(4)" ::: "memory");  // tile0 kh0 resident
  __builtin_amdgcn_s_barrier();

  for (int kt = 0; kt < nk; ++kt) {
    const int cur = kt & 1, nxt = cur ^ 1;
    const long koff = (long)(((kt + 1) < nk) ? (kt + 1) : 0) * BKT;
#pragma unroll
    for (int ks = 0; ks < 2; ++ks) {
      // B fragments for this K-half: read once, live across both mh phases
      bf16x8 bfr[4];
#pragma unroll
      for (int j = 0; j < 4; ++j)
        bfr[j] = *reinterpret_cast<const bf16x8*>(
            &Bs[cur][ks][rdB + (j * 16) * 32]);
#pragma unroll
      for (int mh = 0; mh < 2; ++mh) {
        bf16x8 af[4];
#pragma unroll
        for (int i = 0; i < 4; ++i)
          af[i] = *reinterpret_cast<const bf16x8*>(
              &As[cur][ks][rdA + (mh * 64 + i * 16) * 32]);
        const int p = ks * 2 + mh;
        if (p == 0) {
          GLDS16(aS0 + koff, &As[nxt][0][d0]);
          GLDS16(aS1 + koff, &As[nxt][0][d1]);
        } else if (p == 1) {
          GLDS16(wS0 + koff, &Bs[nxt][0][d0]);
          GLDS16(wS1 + koff, &Bs[nxt][0][d1]);
        } else if (p == 2) {
          GLDS16(aS0 + koff + 32, &As[nxt][1][d0]);
          GLDS16(aS1 + koff + 32, &As[nxt][1][d1]);
        } else {
          GLDS16(wS0 + koff + 32, &Bs[nxt][1][d0]);
          GLDS16(wS1 + koff + 32, &Bs[nxt][1][d1]);
        }
        asm volatile("" ::: "memory");
        __builtin_amdgcn_s_barrier();
        __builtin_amdgcn_s_setprio(1);
#pragma unroll
        for (int i = 0; i < 4; ++i)
#pragma unroll
          for (int j = 0; j < 4; ++j)
            acc[mh * 4 + i][j] = __builtin_amdgcn_mfma_f32_16x16x32_bf16(
                af[i], bfr[j], acc[mh * 4 + i][j], 0, 0, 0);
        __builtin_amdgcn_s_setprio(0);
        // counted waits (never 0 in-loop):
        // p==1: cur.kh1 must be resident before p2/p3 read it
        // p==3: nxt.kh0 must be resident before next tile's p0/p1
        if (p == 1 || p == 3)
          asm volatile("s_waitcnt vmcnt(4)" ::: "memory");
        __builtin_amdgcn_s_barrier();
      }
    }
  }

  // ---- epilogue: C/D frag layout col=lane&15, row=(lane>>4)*4+v
  const long col0 = wRow0 + wn * 64 + (lane & 15);
  float scl[4], bs[4];
#pragma unroll
  for (int j = 0; j < 4; ++j) {
    scl[j] = scale[col0 + j * 16];
    bs[j] = bias[col0 + j * 16];
  }
  const long row0 = aRow0 + wm * 128 + ((lane >> 4) << 2);
#pragma unroll
  for (int i = 0; i < 8; ++i) {
#pragma unroll
    for (int v = 0; v < 4; ++v) {
      float* cp = C + (row0 + i * 16 + v) * (long)N + col0;
#pragma unroll
      for (int j = 0; j < 4; ++j)
        cp[j * 16] = acc[i][j][v] * scl[j] + bs[j];
    }
  }
}

// correctness-only fallback
__global__ void naive_w8a16(const float* __restrict__ inp,
                            const int* __restrict__ qw,
                            const float* __restrict__ scale,
                            const float* __restrict__ bias,
                            float* __restrict__ out, long M, long N, long K) {
  long idx = (long)blockIdx.x * blockDim.x + threadIdx.x;
  if (idx >= M * N) return;
  long col = idx % N, row = idx / N;
  const float* a = inp + row * K;
  const int* w = qw + col * K;
  float s = 0.f;
  for (long k = 0; k < K; k += 4) {
    float4 av = *reinterpret_cast<const float4*>(&a[k]);
    int4 wv = *reinterpret_cast<const int4*>(&w[k]);
    s += av.x * (float)wv.x + av.y * (float)wv.y + av.z * (float)wv.z +
         av.w * (float)wv.w;
  }
  out[idx] = s * scale[col] + bias[col];
}

extern "C" void kernel_launch(void* const* d_in, const int* in_sizes, int n_in,
                              void* d_out, int out_size, void* d_ws,
                              size_t ws_size, hipStream_t stream) {
  const float* inp = (const float*)d_in[0];   // [B,S,D_IN] f32
  const int* qw = (const int*)d_in[1];        // [D_OUT,D_IN] i32
  const float* scale = (const float*)d_in[2]; // [D_OUT]
  const float* bias = (const float*)d_in[3];  // [D_OUT]
  float* out = (float*)d_out;                 // [B,S,D_OUT] f32

  const long N = in_sizes[2];                 // 16384
  const long K = (long)in_sizes[1] / N;       // 4096
  const long M = (long)in_sizes[0] / K;       // 8192

  const size_t aBytes = (size_t)M * K * 2;
  const size_t wBytes = (size_t)N * K * 2;

  if (ws_size >= aBytes + wBytes && (M % BM) == 0 && (N % BN) == 0 &&
      (K % BKT) == 0 && (K / BKT) >= 2) {
    unsigned short* Abf = (unsigned short*)d_ws;
    unsigned short* Wbf = (unsigned short*)((char*)d_ws + aBytes);
    cvt_f32_to_bf16<<<2048, 256, 0, stream>>>(inp, Abf, M * K / 4);
    cvt_i32_to_bf16<<<2048, 256, 0, stream>>>(qw, Wbf, N * K / 4);
    const int nwg = (int)((M / BM) * (N / BN));  // 2048
    gemm256_8ph<<<nwg, 512, 0, stream>>>(Abf, Wbf, scale, bias, out, (int)M,
                                         (int)N, (int)K);
  } else {
    long total = M * N;
    naive_w8a16<<<(int)((total + 255) / 256), 256, 0, stream>>>(
        inp, qw, scale, bias, out, M, N, K);
  }
}

// Round 5
// 1305.034 us; speedup vs baseline: 1.3031x; 1.2306x over previous
//
#include <hip/hip_runtime.h>
#include <stdint.h>

typedef __attribute__((ext_vector_type(8))) __bf16 bf16x8;
typedef __attribute__((ext_vector_type(4))) float f32x4;

#define BM 256
#define BN 256
#define BKT 64   // K elems per tile; split into 2 K-halves of 32

__device__ __forceinline__ unsigned short f2bf_rne(float f) {
  unsigned int u = __builtin_bit_cast(unsigned int, f);
  u += 0x7FFFu + ((u >> 16) & 1u);
  return (unsigned short)(u >> 16);
}

__global__ void cvt_f32_to_bf16(const float* __restrict__ in,
                                unsigned short* __restrict__ out, long n4) {
  long stride = (long)gridDim.x * blockDim.x;
  for (long i = (long)blockIdx.x * blockDim.x + threadIdx.x; i < n4; i += stride) {
    float4 v = reinterpret_cast<const float4*>(in)[i];
    ushort4 o;
    o.x = f2bf_rne(v.x); o.y = f2bf_rne(v.y);
    o.z = f2bf_rne(v.z); o.w = f2bf_rne(v.w);
    reinterpret_cast<ushort4*>(out)[i] = o;
  }
}

__global__ void cvt_i32_to_bf16(const int* __restrict__ in,
                                unsigned short* __restrict__ out, long n4) {
  long stride = (long)gridDim.x * blockDim.x;
  for (long i = (long)blockIdx.x * blockDim.x + threadIdx.x; i < n4; i += stride) {
    int4 v = reinterpret_cast<const int4*>(in)[i];
    ushort4 o;
    o.x = f2bf_rne((float)v.x); o.y = f2bf_rne((float)v.y);
    o.z = f2bf_rne((float)v.z); o.w = f2bf_rne((float)v.w);
    reinterpret_cast<ushort4*>(out)[i] = o;
  }
}

#define GLDS16(g, l)                                                          \
  __builtin_amdgcn_global_load_lds(                                           \
      (const __attribute__((address_space(1))) unsigned int*)(g),             \
      (__attribute__((address_space(3))) unsigned int*)(l), 16, 0, 0)

// Inline-asm ds_read_b128: opaque to SIInsertWaitcnts, so the compiler cannot
// insert conservative vmcnt(0) drains ordering these against global_load_lds
// LDS-DMA writes (runtime cur/nxt buffers can't be disambiguated). All
// lgkm/vm waits in the K-loop are manual (rule #18: lgkmcnt(0)+sched_barrier).
typedef __attribute__((address_space(3))) const unsigned short lds_cu16;

template <int OFF>
__device__ __forceinline__ bf16x8 ldsb128(lds_cu16* p) {
  bf16x8 r;
  asm volatile("ds_read_b128 %0, %1 offset:%2" : "=v"(r) : "v"(p), "i"(OFF));
  return r;
}

// 256x256 8-phase GEMM, T2-swizzled, asm ds_reads + manual counted waits.
// LDS K-half layout [256][32] bf16; within each 1024B chunk (16 rows x 4
// 16B-slots), physical slot (r,s) holds logical (r, s ^ ((r>>1)&3)).
// Write: linear gload_lds dest + inverse-permuted global source column.
// Read: ds_read slot index XORed the same way.
__global__ __launch_bounds__(512, 2) void gemm256_8ph(
    const unsigned short* __restrict__ A,   // [M][K] bf16
    const unsigned short* __restrict__ W,   // [N][K] bf16
    const float* __restrict__ scale,        // [N]
    const float* __restrict__ bias,         // [N]
    float* __restrict__ C,                  // [M][N] f32
    int M, int N, int K) {
  __shared__ __align__(16) unsigned short As[2][2][256 * 32];
  __shared__ __align__(16) unsigned short Bs[2][2][256 * 32];

  const int tid = threadIdx.x;
  const int lane = tid & 63;
  const int wv = tid >> 6;       // 0..7
  const int wm = wv >> 2;        // 0..1  (wave row: 128 rows)
  const int wn = wv & 3;         // 0..3  (wave col: 64 cols)

  const int nwg = gridDim.x;
  const int bid = blockIdx.x;
  const int wg = ((nwg & 7) == 0) ? ((bid & 7) * (nwg >> 3) + (bid >> 3)) : bid;
  const int mT = M / BM;
  const int bm = wg % mT;        // M-fast: neighbors share W panel
  const int bn = wg / mT;

  const long aRow0 = (long)bm * BM;
  const long wRow0 = (long)bn * BN;

  // ---- staging: chunk c = 16 rows x 64B. lane l writes LINEAR dest slot
  // p=l (row r=l>>2, slot s=l&3); it must carry logical slot s^f(r),
  // f(r)=(r>>1)&3 = (l>>3)&3. So source k-offset is swizzled:
  const int c0 = wv, c1 = 8 + wv;
  const int sr0 = 16 * c0 + (lane >> 2);
  const int sr1 = 16 * c1 + (lane >> 2);
  const int sc = (((lane & 3) ^ ((lane >> 3) & 3))) * 8;  // inverse-swz source
  const unsigned short* aS0 = A + (aRow0 + sr0) * (long)K + sc;
  const unsigned short* aS1 = A + (aRow0 + sr1) * (long)K + sc;
  const unsigned short* wS0 = W + (wRow0 + sr0) * (long)K + sc;
  const unsigned short* wS1 = W + (wRow0 + sr1) * (long)K + sc;
  const int d0 = c0 * 512 + lane * 8;   // linear ushort offset in half-region
  const int d1 = c1 * 512 + lane * 8;

  // ---- ds_read bases: row*32 + swizzled-slot*8. Row bits 1..2 within every
  // 16-row block equal (lane>>1)&3, so the XOR term is lane-constant:
  const int sx = (lane >> 4) ^ ((lane >> 1) & 3);
  const int rdA = (wm * 128 + (lane & 15)) * 32 + sx * 8;
  const int rdB = (wn * 64 + (lane & 15)) * 32 + sx * 8;

  f32x4 acc[8][4] = {};

  const int nk = K / BKT;

  // ---- prologue: stage tile 0 (A-kh0, B-kh0, A-kh1, B-kh1)
  GLDS16(aS0, &As[0][0][d0]);
  GLDS16(aS1, &As[0][0][d1]);
  GLDS16(wS0, &Bs[0][0][d0]);
  GLDS16(wS1, &Bs[0][0][d1]);
  GLDS16(aS0 + 32, &As[0][1][d0]);
  GLDS16(aS1 + 32, &As[0][1][d1]);
  GLDS16(wS0 + 32, &Bs[0][1][d0]);
  GLDS16(wS1 + 32, &Bs[0][1][d1]);
  asm volatile("s_waitcnt vmcnt(4)" ::: "memory");  // tile0 kh0 (A+B) resident
  __builtin_amdgcn_s_barrier();

  for (int kt = 0; kt < nk; ++kt) {
    const int cur = kt & 1, nxt = cur ^ 1;
    const long koff = (long)(((kt + 1) < nk) ? (kt + 1) : 0) * BKT;
#pragma unroll
    for (int ks = 0; ks < 2; ++ks) {
      // B fragments for this K-half: read once, live across both mh phases.
      lds_cu16* pB = (lds_cu16*)&Bs[cur][ks][rdB];
      bf16x8 bfr[4];
      bfr[0] = ldsb128<0>(pB);
      bfr[1] = ldsb128<1024>(pB);
      bfr[2] = ldsb128<2048>(pB);
      bfr[3] = ldsb128<3072>(pB);
#pragma unroll
      for (int mh = 0; mh < 2; ++mh) {
        lds_cu16* pA = (lds_cu16*)&As[cur][ks][rdA + mh * 2048];
        bf16x8 af[4];
        af[0] = ldsb128<0>(pA);
        af[1] = ldsb128<1024>(pA);
        af[2] = ldsb128<2048>(pA);
        af[3] = ldsb128<3072>(pA);
        const int p = ks * 2 + mh;
        if (p == 0) {
          GLDS16(aS0 + koff, &As[nxt][0][d0]);
          GLDS16(aS1 + koff, &As[nxt][0][d1]);
        } else if (p == 1) {
          GLDS16(wS0 + koff, &Bs[nxt][0][d0]);
          GLDS16(wS1 + koff, &Bs[nxt][0][d1]);
        } else if (p == 2) {
          GLDS16(aS0 + koff + 32, &As[nxt][1][d0]);
          GLDS16(aS1 + koff + 32, &As[nxt][1][d1]);
        } else {
          GLDS16(wS0 + koff + 32, &Bs[nxt][1][d0]);
          GLDS16(wS1 + koff + 32, &Bs[nxt][1][d1]);
        }
        asm volatile("" ::: "memory");
        __builtin_amdgcn_s_barrier();
        // manual data-arrival wait for the asm ds_reads, then pin the MFMAs
        // below it (rule #18: compiler would otherwise hoist them past it)
        asm volatile("s_waitcnt lgkmcnt(0)" ::: "memory");
        __builtin_amdgcn_sched_barrier(0);
        __builtin_amdgcn_s_setprio(1);
#pragma unroll
        for (int i = 0; i < 4; ++i)
#pragma unroll
          for (int j = 0; j < 4; ++j)
            acc[mh * 4 + i][j] = __builtin_amdgcn_mfma_f32_16x16x32_bf16(
                af[i], bfr[j], acc[mh * 4 + i][j], 0, 0, 0);
        __builtin_amdgcn_s_setprio(0);
        // counted waits (never 0 in-loop); 2 loads issued per phase:
        // p==1: leaves p0+p1's 4 in flight -> prev-issued cur.kh1 resident
        // p==3: leaves p2+p3's 4 in flight -> nxt.kh0 resident for next tile
        if (p == 1 || p == 3)
          asm volatile("s_waitcnt vmcnt(4)" ::: "memory");
        __builtin_amdgcn_s_barrier();
      }
    }
  }

  // ---- epilogue: C/D frag layout col=lane&15, row=(lane>>4)*4+v
  const long col0 = wRow0 + wn * 64 + (lane & 15);
  float scl[4], bs[4];
#pragma unroll
  for (int j = 0; j < 4; ++j) {
    scl[j] = scale[col0 + j * 16];
    bs[j] = bias[col0 + j * 16];
  }
  const long row0 = aRow0 + wm * 128 + ((lane >> 4) << 2);
#pragma unroll
  for (int i = 0; i < 8; ++i) {
#pragma unroll
    for (int v = 0; v < 4; ++v) {
      float* cp = C + (row0 + i * 16 + v) * (long)N + col0;
#pragma unroll
      for (int j = 0; j < 4; ++j)
        cp[j * 16] = acc[i][j][v] * scl[j] + bs[j];
    }
  }
}

// correctness-only fallback
__global__ void naive_w8a16(const float* __restrict__ inp,
                            const int* __restrict__ qw,
                            const float* __restrict__ scale,
                            const float* __restrict__ bias,
                            float* __restrict__ out, long M, long N, long K) {
  long idx = (long)blockIdx.x * blockDim.x + threadIdx.x;
  if (idx >= M * N) return;
  long col = idx % N, row = idx / N;
  const float* a = inp + row * K;
  const int* w = qw + col * K;
  float s = 0.f;
  for (long k = 0; k < K; k += 4) {
    float4 av = *reinterpret_cast<const float4*>(&a[k]);
    int4 wv = *reinterpret_cast<const int4*>(&w[k]);
    s += av.x * (float)wv.x + av.y * (float)wv.y + av.z * (float)wv.z +
         av.w * (float)wv.w;
  }
  out[idx] = s * scale[col] + bias[col];
}

extern "C" void kernel_launch(void* const* d_in, const int* in_sizes, int n_in,
                              void* d_out, int out_size, void* d_ws,
                              size_t ws_size, hipStream_t stream) {
  const float* inp = (const float*)d_in[0];   // [B,S,D_IN] f32
  const int* qw = (const int*)d_in[1];        // [D_OUT,D_IN] i32
  const float* scale = (const float*)d_in[2]; // [D_OUT]
  const float* bias = (const float*)d_in[3];  // [D_OUT]
  float* out = (float*)d_out;                 // [B,S,D_OUT] f32

  const long N = in_sizes[2];                 // 16384
  const long K = (long)in_sizes[1] / N;       // 4096
  const long M = (long)in_sizes[0] / K;       // 8192

  const size_t aBytes = (size_t)M * K * 2;
  const size_t wBytes = (size_t)N * K * 2;

  if (ws_size >= aBytes + wBytes && (M % BM) == 0 && (N % BN) == 0 &&
      (K % BKT) == 0 && (K / BKT) >= 2) {
    unsigned short* Abf = (unsigned short*)d_ws;
    unsigned short* Wbf = (unsigned short*)((char*)d_ws + aBytes);
    cvt_f32_to_bf16<<<2048, 256, 0, stream>>>(inp, Abf, M * K / 4);
    cvt_i32_to_bf16<<<2048, 256, 0, stream>>>(qw, Wbf, N * K / 4);
    const int nwg = (int)((M / BM) * (N / BN));  // 2048
    gemm256_8ph<<<nwg, 512, 0, stream>>>(Abf, Wbf, scale, bias, out, (int)M,
                                         (int)N, (int)K);
  } else {
    long total = M * N;
    naive_w8a16<<<(int)((total + 255) / 256), 256, 0, stream>>>(
        inp, qw, scale, bias, out, M, N, K);
  }
}

// Round 6
// 1293.220 us; speedup vs baseline: 1.3150x; 1.0091x over previous
//
#include <hip/hip_runtime.h>
#include <stdint.h>

typedef __attribute__((ext_vector_type(8))) __bf16 bf16x8;
typedef __attribute__((ext_vector_type(4))) float f32x4;

#define BM 256
#define BN 256
#define BKT 64   // K elems per tile; split into 2 K-halves of 32

__device__ __forceinline__ unsigned short f2bf_rne(float f) {
  unsigned int u = __builtin_bit_cast(unsigned int, f);
  u += 0x7FFFu + ((u >> 16) & 1u);
  return (unsigned short)(u >> 16);
}

__global__ void cvt_f32_to_bf16(const float* __restrict__ in,
                                unsigned short* __restrict__ out, long n4) {
  long stride = (long)gridDim.x * blockDim.x;
  for (long i = (long)blockIdx.x * blockDim.x + threadIdx.x; i < n4; i += stride) {
    float4 v = reinterpret_cast<const float4*>(in)[i];
    ushort4 o;
    o.x = f2bf_rne(v.x); o.y = f2bf_rne(v.y);
    o.z = f2bf_rne(v.z); o.w = f2bf_rne(v.w);
    reinterpret_cast<ushort4*>(out)[i] = o;
  }
}

__global__ void cvt_i32_to_bf16(const int* __restrict__ in,
                                unsigned short* __restrict__ out, long n4) {
  long stride = (long)gridDim.x * blockDim.x;
  for (long i = (long)blockIdx.x * blockDim.x + threadIdx.x; i < n4; i += stride) {
    int4 v = reinterpret_cast<const int4*>(in)[i];
    ushort4 o;
    o.x = f2bf_rne((float)v.x); o.y = f2bf_rne((float)v.y);
    o.z = f2bf_rne((float)v.z); o.w = f2bf_rne((float)v.w);
    reinterpret_cast<ushort4*>(out)[i] = o;
  }
}

#define GLDS16(g, l)                                                          \
  __builtin_amdgcn_global_load_lds(                                           \
      (const __attribute__((address_space(1))) unsigned int*)(g),             \
      (__attribute__((address_space(3))) unsigned int*)(l), 16, 0, 0)

// Inline-asm ds_read_b128 (opaque to SIInsertWaitcnts -> no compiler vmcnt(0)
// drains against the LDS-DMA writes). Manual lgkm/vm waits per rule #18.
typedef __attribute__((address_space(3))) const unsigned short lds_cu16;

template <int OFF>
__device__ __forceinline__ bf16x8 ldsb128(lds_cu16* p) {
  bf16x8 r;
  asm volatile("ds_read_b128 %0, %1 offset:%2" : "=v"(r) : "v"(p), "i"(OFF));
  return r;
}

__device__ __forceinline__ void ld4(lds_cu16* p, bf16x8 r[4]) {
  r[0] = ldsb128<0>(p);
  r[1] = ldsb128<1024>(p);
  r[2] = ldsb128<2048>(p);
  r[3] = ldsb128<3072>(p);
}

__device__ __forceinline__ void mfma16(const bf16x8 af[4], const bf16x8 bfr[4],
                                       f32x4 (*accRow)[4]) {
#pragma unroll
  for (int i = 0; i < 4; ++i)
#pragma unroll
    for (int j = 0; j < 4; ++j)
      accRow[i][j] = __builtin_amdgcn_mfma_f32_16x16x32_bf16(af[i], bfr[j],
                                                             accRow[i][j],
                                                             0, 0, 0);
}

#define CLOB asm volatile("" ::: "memory")
#define BAR __builtin_amdgcn_s_barrier()
#define LGKM0 asm volatile("s_waitcnt lgkmcnt(0)" ::: "memory")
#define SCHEDB __builtin_amdgcn_sched_barrier(0)
#define VMC4 asm volatile("s_waitcnt vmcnt(4)" ::: "memory")

// 256x256 8-phase GEMM, T2-swizzled, asm ds_reads, read-pipelined phases.
// K-half LDS layout [256][32]; within each 1024B chunk (16 rows x 4 16B
// slots), physical slot (r,s) holds logical (r, s ^ ((r>>1)&3)).
// Phases p0/p1 share kh0 and p2/p3 share kh1, so p1's (p3's) A-fragment
// ds_reads are issued INSIDE p0's (p2's) MFMA region - their latency hides
// under the matrix pipe and p1/p3 start MFMA immediately after the barrier.
__global__ __launch_bounds__(512, 2) void gemm256_8ph(
    const unsigned short* __restrict__ A,   // [M][K] bf16
    const unsigned short* __restrict__ W,   // [N][K] bf16
    const float* __restrict__ scale,        // [N]
    const float* __restrict__ bias,         // [N]
    float* __restrict__ C,                  // [M][N] f32
    int M, int N, int K) {
  __shared__ __align__(16) unsigned short As[2][2][256 * 32];
  __shared__ __align__(16) unsigned short Bs[2][2][256 * 32];

  const int tid = threadIdx.x;
  const int lane = tid & 63;
  const int wv = tid >> 6;       // 0..7
  const int wm = wv >> 2;        // 0..1  (wave row: 128 rows)
  const int wn = wv & 3;         // 0..3  (wave col: 64 cols)

  const int nwg = gridDim.x;
  const int bid = blockIdx.x;
  const int wg = ((nwg & 7) == 0) ? ((bid & 7) * (nwg >> 3) + (bid >> 3)) : bid;
  const int mT = M / BM;
  const int bm = wg % mT;        // M-fast: neighbors share W panel
  const int bn = wg / mT;

  const long aRow0 = (long)bm * BM;
  const long wRow0 = (long)bn * BN;

  // staging: chunk c = 16 rows x 64B; lane l -> linear dest slot, inverse-
  // swizzled source column (logical slot s^((l>>3)&3)).
  const int c0 = wv, c1 = 8 + wv;
  const int sr0 = 16 * c0 + (lane >> 2);
  const int sr1 = 16 * c1 + (lane >> 2);
  const int sc = (((lane & 3) ^ ((lane >> 3) & 3))) * 8;
  const unsigned short* aS0 = A + (aRow0 + sr0) * (long)K + sc;
  const unsigned short* aS1 = A + (aRow0 + sr1) * (long)K + sc;
  const unsigned short* wS0 = W + (wRow0 + sr0) * (long)K + sc;
  const unsigned short* wS1 = W + (wRow0 + sr1) * (long)K + sc;
  const int d0 = c0 * 512 + lane * 8;
  const int d1 = c1 * 512 + lane * 8;

  // ds_read bases: row*32 + swizzled-slot*8 (XOR term lane-constant)
  const int sx = (lane >> 4) ^ ((lane >> 1) & 3);
  const int rdA = (wm * 128 + (lane & 15)) * 32 + sx * 8;
  const int rdB = (wn * 64 + (lane & 15)) * 32 + sx * 8;

  f32x4 acc[8][4] = {};

  const int nk = K / BKT;

  // prologue: stage tile 0 (A-kh0, B-kh0, A-kh1, B-kh1)
  GLDS16(aS0, &As[0][0][d0]);
  GLDS16(aS1, &As[0][0][d1]);
  GLDS16(wS0, &Bs[0][0][d0]);
  GLDS16(wS1, &Bs[0][0][d1]);
  GLDS16(aS0 + 32, &As[0][1][d0]);
  GLDS16(aS1 + 32, &As[0][1][d1]);
  GLDS16(wS0 + 32, &Bs[0][1][d0]);
  GLDS16(wS1 + 32, &Bs[0][1][d1]);
  asm volatile("s_waitcnt vmcnt(4)" ::: "memory");  // tile0 kh0 resident
  BAR;

  for (int kt = 0; kt < nk; ++kt) {
    const int cur = kt & 1, nxt = cur ^ 1;
    const long koff = (long)(((kt + 1) < nk) ? (kt + 1) : 0) * BKT;
    bf16x8 bfr[4], af0[4], af1[4];

    // ---- p0: gap = kh0 B + A-mh0 reads, stage A-next-kh0
    ld4((lds_cu16*)&Bs[cur][0][rdB], bfr);
    ld4((lds_cu16*)&As[cur][0][rdA], af0);
    GLDS16(aS0 + koff, &As[nxt][0][d0]);
    GLDS16(aS1 + koff, &As[nxt][0][d1]);
    CLOB; BAR;
    LGKM0; SCHEDB;
    __builtin_amdgcn_s_setprio(1);
    ld4((lds_cu16*)&As[cur][0][rdA + 2048], af1);  // p1's frags, hidden
    mfma16(af0, bfr, &acc[0]);
    __builtin_amdgcn_s_setprio(0);
    CLOB; BAR;

    // ---- p1: gap = stage B-next-kh0 only
    GLDS16(wS0 + koff, &Bs[nxt][0][d0]);
    GLDS16(wS1 + koff, &Bs[nxt][0][d1]);
    CLOB; BAR;
    LGKM0; SCHEDB;               // af1 landed long ago - free
    __builtin_amdgcn_s_setprio(1);
    mfma16(af1, bfr, &acc[4]);
    __builtin_amdgcn_s_setprio(0);
    VMC4;                        // completes prev p2/p3 -> cur.kh1 resident
    CLOB; BAR;

    // ---- p2: gap = kh1 B + A-mh0 reads, stage A-next-kh1
    ld4((lds_cu16*)&Bs[cur][1][rdB], bfr);
    ld4((lds_cu16*)&As[cur][1][rdA], af0);
    GLDS16(aS0 + koff + 32, &As[nxt][1][d0]);
    GLDS16(aS1 + koff + 32, &As[nxt][1][d1]);
    CLOB; BAR;
    LGKM0; SCHEDB;
    __builtin_amdgcn_s_setprio(1);
    ld4((lds_cu16*)&As[cur][1][rdA + 2048], af1);  // p3's frags, hidden
    mfma16(af0, bfr, &acc[0]);
    __builtin_amdgcn_s_setprio(0);
    CLOB; BAR;

    // ---- p3: gap = stage B-next-kh1 only
    GLDS16(wS0 + koff + 32, &Bs[nxt][1][d0]);
    GLDS16(wS1 + koff + 32, &Bs[nxt][1][d1]);
    CLOB; BAR;
    LGKM0; SCHEDB;
    __builtin_amdgcn_s_setprio(1);
    mfma16(af1, bfr, &acc[4]);
    __builtin_amdgcn_s_setprio(0);
    VMC4;                        // completes p0/p1 -> next.kh0 resident
    CLOB; BAR;
  }

  // epilogue: C/D frag layout col=lane&15, row=(lane>>4)*4+v
  const long col0 = wRow0 + wn * 64 + (lane & 15);
  float scl[4], bs[4];
#pragma unroll
  for (int j = 0; j < 4; ++j) {
    scl[j] = scale[col0 + j * 16];
    bs[j] = bias[col0 + j * 16];
  }
  const long row0 = aRow0 + wm * 128 + ((lane >> 4) << 2);
#pragma unroll
  for (int i = 0; i < 8; ++i) {
#pragma unroll
    for (int v = 0; v < 4; ++v) {
      float* cp = C + (row0 + i * 16 + v) * (long)N + col0;
#pragma unroll
      for (int j = 0; j < 4; ++j)
        cp[j * 16] = acc[i][j][v] * scl[j] + bs[j];
    }
  }
}

// correctness-only fallback
__global__ void naive_w8a16(const float* __restrict__ inp,
                            const int* __restrict__ qw,
                            const float* __restrict__ scale,
                            const float* __restrict__ bias,
                            float* __restrict__ out, long M, long N, long K) {
  long idx = (long)blockIdx.x * blockDim.x + threadIdx.x;
  if (idx >= M * N) return;
  long col = idx % N, row = idx / N;
  const float* a = inp + row * K;
  const int* w = qw + col * K;
  float s = 0.f;
  for (long k = 0; k < K; k += 4) {
    float4 av = *reinterpret_cast<const float4*>(&a[k]);
    int4 wv = *reinterpret_cast<const int4*>(&w[k]);
    s += av.x * (float)wv.x + av.y * (float)wv.y + av.z * (float)wv.z +
         av.w * (float)wv.w;
  }
  out[idx] = s * scale[col] + bias[col];
}

extern "C" void kernel_launch(void* const* d_in, const int* in_sizes, int n_in,
                              void* d_out, int out_size, void* d_ws,
                              size_t ws_size, hipStream_t stream) {
  const float* inp = (const float*)d_in[0];   // [B,S,D_IN] f32
  const int* qw = (const int*)d_in[1];        // [D_OUT,D_IN] i32
  const float* scale = (const float*)d_in[2]; // [D_OUT]
  const float* bias = (const float*)d_in[3];  // [D_OUT]
  float* out = (float*)d_out;                 // [B,S,D_OUT] f32

  const long N = in_sizes[2];                 // 16384
  const long K = (long)in_sizes[1] / N;       // 4096
  const long M = (long)in_sizes[0] / K;       // 8192

  const size_t aBytes = (size_t)M * K * 2;
  const size_t wBytes = (size_t)N * K * 2;

  if (ws_size >= aBytes + wBytes && (M % BM) == 0 && (N % BN) == 0 &&
      (K % BKT) == 0 && (K / BKT) >= 2) {
    unsigned short* Abf = (unsigned short*)d_ws;
    unsigned short* Wbf = (unsigned short*)((char*)d_ws + aBytes);
    cvt_f32_to_bf16<<<2048, 256, 0, stream>>>(inp, Abf, M * K / 4);
    cvt_i32_to_bf16<<<2048, 256, 0, stream>>>(qw, Wbf, N * K / 4);
    const int nwg = (int)((M / BM) * (N / BN));  // 2048
    gemm256_8ph<<<nwg, 512, 0, stream>>>(Abf, Wbf, scale, bias, out, (int)M,
                                         (int)N, (int)K);
  } else {
    long total = M * N;
    naive_w8a16<<<(int)((total + 255) / 256), 256, 0, stream>>>(
        inp, qw, scale, bias, out, M, N, K);
  }
}